// Round 2
// baseline (10828.118 us; speedup 1.0000x reference)
//
#include <hip/hip_runtime.h>
#include <math.h>

namespace {

constexpr int Bn = 64, Ln = 256, Cn = 8, Dn = 512, Mn = 512;
constexpr int TWO_M = 2 * Mn;        // 1024
constexpr int PCOLS = 2048;          // 1536 iou (+both biases) | 512 fx (+b_fx)
constexpr size_t P_FLOATS = (size_t)Bn * Ln * PCOLS;   // 33,554,432
constexpr size_t P_BYTES  = P_FLOATS * 4;              // 128 MB

__device__ __forceinline__ float sigmoidf_(float v) { return 1.0f / (1.0f + __expf(-v)); }
__device__ __forceinline__ float dot4_(float4 a, float4 b) {
    return a.x * b.x + a.y * b.y + a.z * b.z + a.w * b.w;
}

// ============================================================================
// Precompute kernel: P[r][0:1536] = x_r @ W_ioux.T + b_ioux + b_iouh
//                    P[r][1536:2048] = x_r @ W_fx.T + b_fx     (r = b*Ln + t)
// ============================================================================
constexpr int GM = 128, GN = 64, GK = 32, GLD = 36;

__global__ __launch_bounds__(256, 4)
void proj_kernel(const float* __restrict__ x,
                 const float* __restrict__ W_ioux, const float* __restrict__ b_ioux,
                 const float* __restrict__ b_iouh,
                 const float* __restrict__ W_fx, const float* __restrict__ b_fx,
                 float* __restrict__ P)
{
    __shared__ float sX[GM * GLD];
    __shared__ float sW[GN * GLD];
    const int tid = threadIdx.x;
    const int rb = blockIdx.x >> 5;       // 0..127
    const int cb = blockIdx.x & 31;       // 0..31
    const int r0 = rb * GM, c0 = cb * GN;
    const bool is_iou = (c0 < 3 * Mn);
    const int rgrp = tid >> 4, cgrp = tid & 15;

    float acc[8][4];
    #pragma unroll
    for (int r = 0; r < 8; ++r)
        #pragma unroll
        for (int c = 0; c < 4; ++c) acc[r][c] = 0.f;

    for (int k0 = 0; k0 < Dn; k0 += GK) {
        #pragma unroll
        for (int i = 0; i < 4; ++i) {
            int flat = i * 256 + tid;
            int row = flat >> 3, kk = flat & 7;
            *(float4*)&sX[row * GLD + kk * 4] =
                *(const float4*)&x[(size_t)(r0 + row) * Dn + k0 + kk * 4];
        }
        #pragma unroll
        for (int i = 0; i < 2; ++i) {
            int flat = i * 256 + tid;
            int row = flat >> 3, kk = flat & 7;
            const float* wsrc = is_iou ? &W_ioux[(size_t)(c0 + row) * Dn]
                                       : &W_fx[(size_t)(c0 - 3 * Mn + row) * Dn];
            *(float4*)&sW[row * GLD + kk * 4] = *(const float4*)&wsrc[k0 + kk * 4];
        }
        __syncthreads();
        #pragma unroll
        for (int k4 = 0; k4 < 8; ++k4) {
            float4 xv[8], wv[4];
            #pragma unroll
            for (int r = 0; r < 8; ++r) xv[r] = *(const float4*)&sX[(rgrp + r * 16) * GLD + k4 * 4];
            #pragma unroll
            for (int c = 0; c < 4; ++c) wv[c] = *(const float4*)&sW[(cgrp + c * 16) * GLD + k4 * 4];
            #pragma unroll
            for (int r = 0; r < 8; ++r)
                #pragma unroll
                for (int c = 0; c < 4; ++c) acc[r][c] += dot4_(xv[r], wv[c]);
        }
        __syncthreads();
    }
    #pragma unroll
    for (int c = 0; c < 4; ++c) {
        int col = c0 + cgrp + c * 16;
        float bias = is_iou ? (b_ioux[col] + b_iouh[col]) : b_fx[col - 3 * Mn];
        #pragma unroll
        for (int r = 0; r < 8; ++r) {
            int row = r0 + rgrp + r * 16;
            P[(size_t)row * PCOLS + col] = acc[r][c] + bias;
        }
    }
}

// ============================================================================
// Step kernel: grid 256 = 32 m-tiles(16 cols) x 8 batch-tiles(8 rows), 512 thr
// ============================================================================
constexpr int NBM = 32, MT = 16, BT = 8;
constexpr int ROWS = BT * Cn;        // 64 gathered child rows
constexpr int KC = 256;              // k-chunk
constexpr int LDR = 268;             // s_ch / s_wfh row stride (~2-way banks)
constexpr int LDC = 520;             // s_chs row stride

constexpr int S_CH  = 0;
constexpr int S_WFH = S_CH + ROWS * LDR;     // 17152
constexpr int S_CHS = S_WFH + MT * LDR;      // 21440
constexpr int S_CS  = S_CHS + BT * LDC;      // 25600
constexpr int S_FD  = S_CS + ROWS * MT;      // 26624
constexpr int S_IOU = S_FD + ROWS * MT;      // 27648
constexpr int S_XMC = S_IOU + 48 * BT;       // 28032
constexpr int S_XM  = S_XMC + ROWS;          // 28096
constexpr int S_BFH = S_XM + BT;             // 28104
constexpr int S_XC  = S_BFH + MT;            // 28120
constexpr int LDS2_FLOATS = S_XC + ROWS;     // 28184
constexpr size_t LDS2_BYTES = (size_t)LDS2_FLOATS * 4;   // 112736
static_assert(LDS2_BYTES <= 160 * 1024, "step LDS over budget");

__global__ __launch_bounds__(512)
void step2_kernel(const int* __restrict__ x_c, const float* __restrict__ x_m,
                  const float* __restrict__ x_m_c,
                  const float* __restrict__ W_iouh, const float* __restrict__ W_fh,
                  const float* __restrict__ b_fh, const float* __restrict__ P,
                  float* __restrict__ out, int t)
{
    extern __shared__ float lds[];
    float* s_ch  = lds + S_CH;
    float* s_wfh = lds + S_WFH;
    float* s_chs = lds + S_CHS;
    float* s_cs  = lds + S_CS;
    float* s_fd  = lds + S_FD;
    float* s_iou = lds + S_IOU;
    float* s_xmc = lds + S_XMC;
    float* s_xm  = lds + S_XM;
    float* s_bfh = lds + S_BFH;
    int*   s_xc  = (int*)(lds + S_XC);

    const int tid = threadIdx.x;
    const int mt = blockIdx.x & (NBM - 1);
    const int bt = blockIdx.x >> 5;
    const int m0 = mt * MT;
    const int b0 = bt * BT;

    if (tid < ROWS) {
        int b = tid >> 3, c = tid & 7;
        s_xc[tid]  = x_c[((size_t)(b0 + b) * Ln + t) * Cn + c];
        s_xmc[tid] = x_m_c[((size_t)(b0 + b) * Ln + t) * Cn + c];
    } else if (tid < ROWS + BT) {
        int b = tid - ROWS;
        s_xm[b] = x_m[(size_t)(b0 + b) * Ln + t];
    } else if (tid < ROWS + BT + MT) {
        s_bfh[tid - ROWS - BT] = b_fh[m0 + (tid - ROWS - BT)];
    }
    __syncthreads();

    // c_s gather (cols m0..m0+15 only)
    if (tid < 256) {
        int row = tid >> 2, js = tid & 3;
        int idx = s_xc[row];
        float4 v = make_float4(0.f, 0.f, 0.f, 0.f);
        if (idx < t)
            v = *(const float4*)&out[((size_t)(b0 + (row >> 3)) * Ln + idx) * TWO_M + m0 + js * 4];
        *(float4*)&s_cs[row * MT + js * 4] = v;
    }

    float accf[4][4];
    #pragma unroll
    for (int r = 0; r < 4; ++r)
        #pragma unroll
        for (int c = 0; c < 4; ++c) accf[r][c] = 0.f;
    const int rowblk = tid >> 5, colblk = (tid >> 3) & 3, ks = tid & 7;

    for (int chunk = 0; chunk < 2; ++chunk) {
        // gather c_h chunk: 64 rows x 256 k
        #pragma unroll
        for (int i = 0; i < 8; ++i) {
            int flat = i * 512 + tid;
            int row = flat >> 6, kslot = flat & 63;
            int idx = s_xc[row];
            float4 v = make_float4(0.f, 0.f, 0.f, 0.f);
            if (idx < t)
                v = *(const float4*)&out[((size_t)(b0 + (row >> 3)) * Ln + idx) * TWO_M
                                         + Mn + chunk * KC + kslot * 4];
            *(float4*)&s_ch[row * LDR + kslot * 4] = v;
        }
        // stage W_fh chunk: 16 cols x 256 k
        #pragma unroll
        for (int i = 0; i < 2; ++i) {
            int flat = i * 512 + tid;
            int col = flat >> 6, kslot = flat & 63;
            *(float4*)&s_wfh[col * LDR + kslot * 4] =
                *(const float4*)&W_fh[(size_t)(m0 + col) * Dn + chunk * KC + kslot * 4];
        }
        __syncthreads();

        // child_h_sum for this k-chunk
        {
            int b = tid >> 6, kslot = tid & 63;
            float4 a = make_float4(0.f, 0.f, 0.f, 0.f);
            #pragma unroll
            for (int c = 0; c < Cn; ++c) {
                float w = s_xmc[b * 8 + c];
                float4 v = *(const float4*)&s_ch[(b * 8 + c) * LDR + kslot * 4];
                a.x += w * v.x; a.y += w * v.y; a.z += w * v.z; a.w += w * v.w;
            }
            *(float4*)&s_chs[b * LDC + chunk * KC + kslot * 4] = a;
        }
        // G2 partial: c_h(64 rows) @ W_fh.T(16 cols), k-split 8 (interleaved)
        #pragma unroll
        for (int kk = 0; kk < 8; ++kk) {
            float4 ch[4], wf[4];
            #pragma unroll
            for (int r = 0; r < 4; ++r)
                ch[r] = *(const float4*)&s_ch[(rowblk * 4 + r) * LDR + ks * 4 + kk * 32];
            #pragma unroll
            for (int c = 0; c < 4; ++c)
                wf[c] = *(const float4*)&s_wfh[(colblk * 4 + c) * LDR + ks * 4 + kk * 32];
            #pragma unroll
            for (int r = 0; r < 4; ++r)
                #pragma unroll
                for (int c = 0; c < 4; ++c)
                    accf[r][c] += dot4_(ch[r], wf[c]);
        }
        __syncthreads();
    }

    // G2 reduce over ks (8-lane groups) -> s_fd
    #pragma unroll
    for (int r = 0; r < 4; ++r)
        #pragma unroll
        for (int c = 0; c < 4; ++c) {
            float v = accf[r][c];
            v += __shfl_xor(v, 1);
            v += __shfl_xor(v, 2);
            v += __shfl_xor(v, 4);
            accf[r][c] = v;
        }
    if (ks == 0) {
        #pragma unroll
        for (int r = 0; r < 4; ++r)
            #pragma unroll
            for (int c = 0; c < 4; ++c)
                s_fd[(rowblk * 4 + r) * MT + colblk * 4 + c] = accf[r][c];
    }

    // G1: child_h_sum(8 rows) @ W_iouh.T (48 cols = 3 strips x 16), k-split 8
    if (tid < 384) {
        const int colid = tid >> 3, ksg = tid & 7;
        const int s = colid >> 4, jj = colid & 15;
        const float* wrow = &W_iouh[(size_t)(s * Mn + m0 + jj) * Mn];
        float acc[BT];
        #pragma unroll
        for (int b = 0; b < BT; ++b) acc[b] = 0.f;
        #pragma unroll 4
        for (int kk = 0; kk < 16; ++kk) {
            const int k = ksg * 4 + kk * 32;
            const float4 w = *(const float4*)&wrow[k];
            #pragma unroll
            for (int b = 0; b < BT; ++b) {
                const float4 h = *(const float4*)&s_chs[b * LDC + k];
                acc[b] += dot4_(h, w);
            }
        }
        #pragma unroll
        for (int b = 0; b < BT; ++b) {
            float v = acc[b];
            v += __shfl_xor(v, 1);
            v += __shfl_xor(v, 2);
            v += __shfl_xor(v, 4);
            acc[b] = v;
        }
        if (ksg == 0) {
            #pragma unroll
            for (int b = 0; b < BT; ++b) s_iou[colid * BT + b] = acc[b];
        }
    }
    __syncthreads();

    // gates + blend + store
    if (tid < BT * MT) {
        const int b = tid >> 4, j = tid & 15;
        const size_t pbase = ((size_t)(b0 + b) * Ln + t) * (size_t)PCOLS;
        const float iv  = s_iou[(0 * MT + j) * BT + b] + P[pbase + 0 * Mn + m0 + j];
        const float ov  = s_iou[(1 * MT + j) * BT + b] + P[pbase + 1 * Mn + m0 + j];
        const float uv  = s_iou[(2 * MT + j) * BT + b] + P[pbase + 2 * Mn + m0 + j];
        const float fxv =                                P[pbase + 3 * Mn + m0 + j];
        const float i_ = sigmoidf_(iv);
        const float o_ = sigmoidf_(ov);
        const float u_ = tanhf(uv);
        const float bfh = s_bfh[j];
        float facc = 0.f;
        #pragma unroll
        for (int c = 0; c < Cn; ++c) {
            const int row = b * 8 + c;
            const float f = sigmoidf_(s_fd[row * MT + j] + bfh + fxv);
            facc += f * s_cs[row * MT + j] * s_xmc[row];
        }
        const float cv = i_ * u_ + facc;
        const float hv = o_ * tanhf(cv);
        const float mval = s_xm[b];
        const size_t obase  = ((size_t)(b0 + b) * Ln + t) * TWO_M;
        const size_t opbase = ((size_t)(b0 + b) * Ln + (t - 1)) * TWO_M;
        out[obase + m0 + j]      = mval * cv + (1.f - mval) * out[opbase + m0 + j];
        out[obase + Mn + m0 + j] = mval * hv + (1.f - mval) * out[opbase + Mn + m0 + j];
    }
}

// ============================================================================
// Legacy monolithic step kernel (fallback when ws is too small for P)
// ============================================================================
constexpr int LBT = 4, LMT = 32, LNMT = Mn / LMT, LPAD = 4, LDK = Dn + LPAD;
constexpr int L_U16 = 4096, L_CHS = LBT * LDK, L_CH = LBT * Cn * LDK,
              L_WFH = LMT * LDK, L_CS = LBT * Cn * LMT, L_IOUF = 4 * LBT * LMT;
constexpr int L_FLOATS = L_U16 + L_CHS + L_CH + L_WFH + L_CS + L_IOUF + 32 + 4 + 32;
constexpr size_t L_BYTES = (size_t)L_FLOATS * 4;

__global__ __launch_bounds__(256, 1)
void step_legacy(const float* __restrict__ x, const int* __restrict__ x_c,
                 const float* __restrict__ x_m, const float* __restrict__ x_m_c,
                 const float* __restrict__ W_ioux, const float* __restrict__ b_ioux,
                 const float* __restrict__ W_iouh, const float* __restrict__ b_iouh,
                 const float* __restrict__ W_fx, const float* __restrict__ b_fx,
                 const float* __restrict__ W_fh, const float* __restrict__ b_fh,
                 float* __restrict__ out, int t)
{
    extern __shared__ float lds[];
    float* u16    = lds;
    float* s_chs  = u16 + L_U16;
    float* s_ch   = s_chs + L_CHS;
    float* s_wfh  = s_ch + L_CH;
    float* s_cs   = s_wfh + L_WFH;
    float* s_iouf = s_cs + L_CS;
    float* s_xmc  = s_iouf + L_IOUF;
    float* s_xm   = s_xmc + 32;
    int*   s_xc   = (int*)(s_xm + 4);

    const int tid = threadIdx.x;
    const int mt = blockIdx.x & (LNMT - 1);
    const int bt = blockIdx.x >> 4;
    const int b0 = bt * LBT, m0 = mt * LMT;

    #pragma unroll
    for (int i = 0; i < 8; ++i) {
        int flat = i * 256 + tid, b = flat >> 9, k = flat & 511;
        u16[b * LDK + k] = x[((size_t)(b0 + b) * Ln + t) * Dn + k];
    }
    if (tid < 32) {
        int b = tid >> 3, c = tid & 7;
        s_xc[tid]  = x_c[((size_t)(b0 + b) * Ln + t) * Cn + c];
        s_xmc[tid] = x_m_c[((size_t)(b0 + b) * Ln + t) * Cn + c];
    }
    if (tid < 4) s_xm[tid] = x_m[(size_t)(b0 + tid) * Ln + t];
    for (int i = 0; i < 64; ++i) {
        int flat = i * 256 + tid, j = flat >> 9, k = flat & 511;
        s_wfh[j * LDK + k] = W_fh[(size_t)(m0 + j) * Dn + k];
    }
    __syncthreads();

    #pragma unroll
    for (int i = 0; i < 8; ++i) {
        int flat = i * 256 + tid, b = flat >> 9, k = flat & 511;
        float acc = 0.f;
        #pragma unroll
        for (int c = 0; c < Cn; ++c) {
            int idx = s_xc[b * 8 + c];
            float v = 0.f;
            if (idx < t) v = out[((size_t)(b0 + b) * Ln + idx) * TWO_M + Mn + k];
            s_ch[(b * 8 + c) * LDK + k] = v;
            acc += s_xmc[b * 8 + c] * v;
        }
        s_chs[b * LDK + k] = acc;
    }
    #pragma unroll
    for (int i = 0; i < 4; ++i) {
        int flat = i * 256 + tid;
        int b = flat >> 8, rem = flat & 255, c = rem >> 5, j = rem & 31;
        int idx = s_xc[b * 8 + c];
        float v = 0.f;
        if (idx < t) v = out[((size_t)(b0 + b) * Ln + idx) * TWO_M + m0 + j];
        s_cs[flat] = v;
    }
    __syncthreads();

    {
        const int unit = tid >> 3, ksl = tid & 7, s = unit >> 3, jg = unit & 7;
        float acc[4][4];
        #pragma unroll
        for (int b = 0; b < 4; ++b)
            #pragma unroll
            for (int jj = 0; jj < 4; ++jj) acc[b][jj] = 0.f;
        if (s < 3) {
            const int colbase = s * Mn + m0 + jg * 4;
            #pragma unroll 4
            for (int it = 0; it < 16; ++it) {
                const int k = it * 32 + ksl * 4;
                float4 sx[4], sc[4];
                #pragma unroll
                for (int b = 0; b < 4; ++b) {
                    sx[b] = *(const float4*)&u16[b * LDK + k];
                    sc[b] = *(const float4*)&s_chs[b * LDK + k];
                }
                #pragma unroll
                for (int jj = 0; jj < 4; ++jj) {
                    const float4 wx = *(const float4*)&W_ioux[(size_t)(colbase + jj) * Dn + k];
                    const float4 wh = *(const float4*)&W_iouh[(size_t)(colbase + jj) * Dn + k];
                    #pragma unroll
                    for (int b = 0; b < 4; ++b)
                        acc[b][jj] += dot4_(sx[b], wx) + dot4_(sc[b], wh);
                }
            }
        } else {
            const int colbase = m0 + jg * 4;
            #pragma unroll 4
            for (int it = 0; it < 16; ++it) {
                const int k = it * 32 + ksl * 4;
                float4 sx[4];
                #pragma unroll
                for (int b = 0; b < 4; ++b) sx[b] = *(const float4*)&u16[b * LDK + k];
                #pragma unroll
                for (int jj = 0; jj < 4; ++jj) {
                    const float4 wx = *(const float4*)&W_fx[(size_t)(colbase + jj) * Dn + k];
                    #pragma unroll
                    for (int b = 0; b < 4; ++b) acc[b][jj] += dot4_(sx[b], wx);
                }
            }
        }
        __syncthreads();
        #pragma unroll
        for (int b = 0; b < 4; ++b)
            #pragma unroll
            for (int jj = 0; jj < 4; ++jj)
                u16[unit * 128 + ksl * 16 + b * 4 + jj] = acc[b][jj];
        __syncthreads();
        #pragma unroll
        for (int e = 0; e < 2; ++e) {
            const int task = e * 256 + tid;
            const int unit2 = task >> 4, rem = task & 15;
            float v = 0.f;
            #pragma unroll
            for (int k2 = 0; k2 < 8; ++k2) v += u16[unit2 * 128 + k2 * 16 + rem];
            const int s2 = unit2 >> 3, jg2 = unit2 & 7;
            const int bb = rem >> 2, jj = rem & 3, j = jg2 * 4 + jj;
            float bias = (s2 < 3) ? (b_ioux[s2 * Mn + m0 + j] + b_iouh[s2 * Mn + m0 + j])
                                  : b_fx[m0 + j];
            s_iouf[(s2 * 4 + bb) * 32 + j] = v + bias;
        }
    }
    __syncthreads();

    {
        const int pos = tid >> 2, ksc = tid & 3, rg = pos >> 3, jg = pos & 7;
        float acc[4][4];
        #pragma unroll
        for (int r = 0; r < 4; ++r)
            #pragma unroll
            for (int j = 0; j < 4; ++j) acc[r][j] = 0.f;
        #pragma unroll 4
        for (int it = 0; it < 32; ++it) {
            const int k = it * 16 + ksc * 4;
            float4 ch[4], wf[4];
            #pragma unroll
            for (int r = 0; r < 4; ++r) ch[r] = *(const float4*)&s_ch[(rg * 4 + r) * LDK + k];
            #pragma unroll
            for (int j = 0; j < 4; ++j) wf[j] = *(const float4*)&s_wfh[(jg * 4 + j) * LDK + k];
            #pragma unroll
            for (int r = 0; r < 4; ++r)
                #pragma unroll
                for (int j = 0; j < 4; ++j) acc[r][j] += dot4_(ch[r], wf[j]);
        }
        #pragma unroll
        for (int r = 0; r < 4; ++r)
            #pragma unroll
            for (int j = 0; j < 4; ++j)
                u16[((rg * 4 + r) * 32 + (jg * 4 + j)) * 4 + ksc] = acc[r][j];
    }
    __syncthreads();

    if (tid < 128) {
        const int b = tid >> 5, j = tid & 31;
        const float iv  = s_iouf[(0 * 4 + b) * 32 + j];
        const float ov  = s_iouf[(1 * 4 + b) * 32 + j];
        const float uv  = s_iouf[(2 * 4 + b) * 32 + j];
        const float fxv = s_iouf[(3 * 4 + b) * 32 + j];
        const float i_ = sigmoidf_(iv), o_ = sigmoidf_(ov), u_ = tanhf(uv);
        const float bfh = b_fh[m0 + j];
        float facc = 0.f;
        #pragma unroll
        for (int c = 0; c < Cn; ++c) {
            const int row = b * 8 + c;
            const float fd = u16[(row * 32 + j) * 4 + 0] + u16[(row * 32 + j) * 4 + 1]
                           + u16[(row * 32 + j) * 4 + 2] + u16[(row * 32 + j) * 4 + 3];
            const float f = sigmoidf_(fd + bfh + fxv);
            facc += f * s_cs[row * 32 + j] * s_xmc[row];
        }
        const float cval = i_ * u_ + facc;
        const float hval = o_ * tanhf(cval);
        const float mval = s_xm[b];
        const size_t base  = ((size_t)(b0 + b) * Ln + t) * TWO_M;
        const size_t pbase = ((size_t)(b0 + b) * Ln + (t - 1)) * TWO_M;
        out[base + m0 + j]      = mval * cval + (1.f - mval) * out[pbase + m0 + j];
        out[base + Mn + m0 + j] = mval * hval + (1.f - mval) * out[pbase + Mn + m0 + j];
    }
}

__global__ void zero_row0(float* __restrict__ out) {
    int i = blockIdx.x * 256 + threadIdx.x;
    int b = i >> 10, j = i & 1023;
    out[(size_t)b * Ln * TWO_M + j] = 0.f;
}

__global__ void final_copy(const float* __restrict__ out, float* __restrict__ fin) {
    int i = blockIdx.x * 256 + threadIdx.x;
    int b = i >> 10, j = i & 1023;
    fin[i] = out[((size_t)b * Ln + (Ln - 1)) * TWO_M + j];
}

} // namespace

extern "C" void kernel_launch(void* const* d_in, const int* in_sizes, int n_in,
                              void* d_out, int out_size, void* d_ws, size_t ws_size,
                              hipStream_t stream) {
    (void)in_sizes; (void)n_in; (void)out_size;
    const float* x      = (const float*)d_in[0];
    const int*   x_c    = (const int*)d_in[1];
    const float* x_m    = (const float*)d_in[2];
    const float* x_m_c  = (const float*)d_in[3];
    const float* W_ioux = (const float*)d_in[4];
    const float* b_ioux = (const float*)d_in[5];
    const float* W_iouh = (const float*)d_in[6];
    const float* b_iouh = (const float*)d_in[7];
    const float* W_fx   = (const float*)d_in[8];
    const float* b_fx   = (const float*)d_in[9];
    const float* W_fh   = (const float*)d_in[10];
    const float* b_fh   = (const float*)d_in[11];
    float* out = (float*)d_out;
    float* fin = out + (size_t)Bn * Ln * TWO_M;

    static bool attr_set = false;
    if (!attr_set) {
        hipFuncSetAttribute((const void*)step2_kernel,
                            hipFuncAttributeMaxDynamicSharedMemorySize, (int)LDS2_BYTES);
        hipFuncSetAttribute((const void*)step_legacy,
                            hipFuncAttributeMaxDynamicSharedMemorySize, (int)L_BYTES);
        attr_set = true;
    }

    hipLaunchKernelGGL(zero_row0, dim3(256), dim3(256), 0, stream, out);

    if (ws_size >= P_BYTES) {
        float* P = (float*)d_ws;
        hipLaunchKernelGGL(proj_kernel, dim3(4096), dim3(256), 0, stream,
                           x, W_ioux, b_ioux, b_iouh, W_fx, b_fx, P);
        for (int t = 1; t < Ln; ++t) {
            hipLaunchKernelGGL(step2_kernel, dim3(256), dim3(512), LDS2_BYTES, stream,
                               x_c, x_m, x_m_c, W_iouh, W_fh, b_fh, P, out, t);
        }
    } else {
        for (int t = 1; t < Ln; ++t) {
            hipLaunchKernelGGL(step_legacy, dim3(256), dim3(256), L_BYTES, stream,
                               x, x_c, x_m, x_m_c, W_ioux, b_ioux, W_iouh, b_iouh,
                               W_fx, b_fx, W_fh, b_fh, out, t);
        }
    }
    hipLaunchKernelGGL(final_copy, dim3(256), dim3(256), 0, stream, out, fin);
}